// Round 9
// baseline (280.280 us; speedup 1.0000x reference)
//
#include <hip/hip_runtime.h>
#include <hip/hip_bf16.h>
#include <hip/hip_cooperative_groups.h>

namespace cg = cooperative_groups;

#define N_NODES 50000
#define N_EDGES 800000
#define D 128

#define COOP_BLOCKS 512
#define PROJ_SPLIT  391          // blocks [0,391): 2 proj tiles each (782 tiles)
#define HIST_BLOCKS (COOP_BLOCKS - PROJ_SPLIT)   // 121
#define CHUNK 98                 // coop scan chunk (512*98 = 50176 >= 50000)
#define SCAN_T 1024
#define PER_T 50                 // discrete scan: 1000 threads x 50

typedef __attribute__((ext_vector_type(8))) short short8;
typedef __attribute__((ext_vector_type(4))) float floatx4;

__device__ __forceinline__ float bfbits2f(unsigned short u) {
    union { unsigned int i; float f; } c; c.i = ((unsigned int)u) << 16; return c.f;
}
__device__ __forceinline__ unsigned short f2bfbits(float f) {
    __hip_bfloat16 h = __float2bfloat16(f);
    return *reinterpret_cast<unsigned short*>(&h);
}

// ---------------------------------------------------------------------------
// One 64-node x 384-col projection MFMA tile (shared by coop + discrete paths)
// ---------------------------------------------------------------------------
__device__ __forceinline__ void proj_tile(
    const int m0, const int tid,
    const float* __restrict__ x, const short* __restrict__ Wts,
    const float* __restrict__ bq, const float* __restrict__ bk,
    const float* __restrict__ bv,
    unsigned short* __restrict__ Qb, unsigned int* __restrict__ KVi,
    short (*xs)[136])
{
    const int lane = tid & 63;
    const int wv   = tid >> 6;
    const int cb   = wv * 32;
    const int lr   = lane & 15;
    const int hi   = lane >> 4;

    __syncthreads();   // xs reuse guard (prev tile / prev phase)

    // stage x tile (64 rows x 128 f32 -> bf16 LDS)
    {
        const int row = tid >> 2;
        const int c0  = (tid & 3) * 32;
        int n = m0 + row; if (n >= N_NODES) n = N_NODES - 1;
        const float* xr = x + (size_t)n * D + c0;
        #pragma unroll
        for (int i = 0; i < 8; ++i) {
            const float4 f = *(const float4*)(xr + i * 4);
            short4 s;
            s.x = (short)f2bfbits(f.x); s.y = (short)f2bfbits(f.y);
            s.z = (short)f2bfbits(f.z); s.w = (short)f2bfbits(f.w);
            *(short4*)(&xs[row][c0 + i * 4]) = s;
        }
    }
    __syncthreads();

    floatx4 acc[3][4][2];   // [p][rt][ct]
    #pragma unroll
    for (int p = 0; p < 3; ++p)
        #pragma unroll
        for (int rt = 0; rt < 4; ++rt)
            #pragma unroll
            for (int ct = 0; ct < 2; ++ct)
                acc[p][rt][ct] = (floatx4){0.f, 0.f, 0.f, 0.f};

    #pragma unroll
    for (int ks = 0; ks < 4; ++ks) {
        const int k0 = ks * 32 + hi * 8;
        short8 bfr[3][2];
        #pragma unroll
        for (int p = 0; p < 3; ++p)
            #pragma unroll
            for (int ct = 0; ct < 2; ++ct) {
                const int col = cb + ct * 16 + lr;
                bfr[p][ct] = *(const short8*)(Wts + ((size_t)(p * D + col) * D + k0));
            }
        short8 afr[4];
        #pragma unroll
        for (int rt = 0; rt < 4; ++rt)
            afr[rt] = *(const short8*)(&xs[rt * 16 + lr][k0]);

        #pragma unroll
        for (int p = 0; p < 3; ++p)
            #pragma unroll
            for (int ct = 0; ct < 2; ++ct)
                #pragma unroll
                for (int rt = 0; rt < 4; ++rt)
                    acc[p][rt][ct] = __builtin_amdgcn_mfma_f32_16x16x32_bf16(
                        afr[rt], bfr[p][ct], acc[p][rt][ct], 0, 0, 0);
    }

    // KVi: bias + packed u32 stores
    #pragma unroll
    for (int ct = 0; ct < 2; ++ct) {
        const int col = cb + ct * 16 + lr;
        const float bkv = bk[col], bvv = bv[col];
        #pragma unroll
        for (int rt = 0; rt < 4; ++rt) {
            const int node0 = m0 + rt * 16 + hi * 4;
            if (node0 < N_NODES) {   // node0%4==0, N%4==0 -> all 4 valid
                #pragma unroll
                for (int r = 0; r < 4; ++r) {
                    const unsigned int kk = f2bfbits(acc[1][rt][ct][r] + bkv);
                    const unsigned int vv = f2bfbits(acc[2][rt][ct][r] + bvv);
                    KVi[(size_t)(node0 + r) * 128 + col] = kk | (vv << 16);
                }
            }
        }
    }

    // Q: transpose through LDS -> coalesced row-major stores
    __syncthreads();
    #pragma unroll
    for (int ct = 0; ct < 2; ++ct) {
        const int col = cb + ct * 16 + lr;
        const float bqv = bq[col];
        #pragma unroll
        for (int rt = 0; rt < 4; ++rt) {
            const int nloc = rt * 16 + hi * 4;
            #pragma unroll
            for (int r = 0; r < 4; ++r)
                xs[nloc + r][col] = (short)f2bfbits(acc[0][rt][ct][r] + bqv);
        }
    }
    __syncthreads();
    {
        const int row = tid >> 2;
        const int c0  = (tid & 3) * 32;
        const int n   = m0 + row;
        if (n < N_NODES) {
            int4* dstp = (int4*)(Qb + (size_t)n * D + c0);
            const int4* srcp = (const int4*)(&xs[row][c0]);
            #pragma unroll
            for (int i = 0; i < 4; ++i) dstp[i] = srcp[i];
        }
    }
}

__device__ __forceinline__ void hist_loop(
    const int rel_bid, const int nblocks, const int tid,
    const int* __restrict__ dst, int* __restrict__ counts)
{
    const int i0 = rel_bid * 256 + tid;
    const int stride = nblocks * 256;
    for (int e = i0; e < N_EDGES; e += stride)
        atomicAdd(&counts[dst[e]], 1);
}

// ===========================================================================
// Cooperative single-kernel build: prep + {proj || hist} + scan + scatter
// ===========================================================================
__global__ __launch_bounds__(256, 2) void build_kernel(
    const float* __restrict__ x,
    const int* __restrict__ src, const int* __restrict__ dst,
    const float* __restrict__ Wq, const float* __restrict__ bq,
    const float* __restrict__ Wk, const float* __restrict__ bk,
    const float* __restrict__ Wv, const float* __restrict__ bv,
    __hip_bfloat16* __restrict__ Wt,
    unsigned short* __restrict__ Qb, unsigned int* __restrict__ KVi,
    int* __restrict__ counts, int* __restrict__ row_ptr,
    int* __restrict__ cursor, int* __restrict__ blksum,
    int* __restrict__ srcs)
{
    cg::grid_group grid = cg::this_grid();
    const int tid  = threadIdx.x;
    const int bid  = blockIdx.x;
    const int gtid = bid * 256 + tid;

    __shared__ short xs[64][136];
    __shared__ int aux[4];

    // Phase A: zero counts + Wt = bf16(W^T)
    if (gtid < N_NODES) counts[gtid] = 0;
    if (gtid < 3 * D * D) {
        const int p = gtid >> 14;
        const int r = gtid & (D * D - 1);
        const int col = r >> 7;
        const int k = r & (D - 1);
        const float* W = (p == 0) ? Wq : (p == 1) ? Wk : Wv;
        Wt[gtid] = __float2bfloat16(W[k * D + col]);
    }
    __threadfence();
    grid.sync();

    // Phase B: proj tiles || histogram
    if (bid < PROJ_SPLIT) {
        const short* Wts = (const short*)Wt;
        proj_tile(bid * 2 * 64,       tid, x, Wts, bq, bk, bv, Qb, KVi, xs);
        proj_tile((bid * 2 + 1) * 64, tid, x, Wts, bq, bk, bv, Qb, KVi, xs);
    } else {
        hist_loop(bid - PROJ_SPLIT, HIST_BLOCKS, tid, dst, counts);
    }
    __threadfence();
    grid.sync();

    // Phase C1: per-chunk local exclusive scan
    {
        int* sd = (int*)xs;
        const int base = bid * CHUNK;
        int v = 0;
        if (tid < 128) {
            if (tid < CHUNK) {
                const int idx = base + tid;
                if (idx < N_NODES) v = counts[idx];
            }
            sd[tid] = v;
        }
        __syncthreads();
        #pragma unroll
        for (int off = 1; off < 128; off <<= 1) {
            int t = 0;
            if (tid < 128 && tid >= off) t = sd[tid - off];
            __syncthreads();
            if (tid < 128) sd[tid] += t;
            __syncthreads();
        }
        if (tid < CHUNK) {
            const int idx = base + tid;
            if (idx < N_NODES) row_ptr[idx] = sd[tid] - v;   // local exclusive
        }
        if (tid == 127) blksum[bid] = sd[127];
    }
    __threadfence();
    grid.sync();

    // Phase C2: add global chunk offsets
    {
        int part = 0;
        for (int j = tid; j < bid; j += 256) part += blksum[j];
        #pragma unroll
        for (int off = 32; off > 0; off >>= 1) part += __shfl_down(part, off);
        if ((tid & 63) == 0) aux[tid >> 6] = part;
        __syncthreads();
        const int off4 = aux[0] + aux[1] + aux[2] + aux[3];

        const int base = bid * CHUNK;
        if (tid < CHUNK) {
            const int idx = base + tid;
            if (idx < N_NODES) {
                const int rp = row_ptr[idx] + off4;
                row_ptr[idx] = rp;
                cursor[idx]  = rp;
            }
        }
        if (bid == COOP_BLOCKS - 1 && tid == 0) row_ptr[N_NODES] = N_EDGES;
    }
    __threadfence();
    grid.sync();

    // Phase D: scatter srcs into CSR order
    for (int e = gtid; e < N_EDGES; e += COOP_BLOCKS * 256) {
        const int pos = atomicAdd(&cursor[dst[e]], 1);
        srcs[pos] = src[e];
    }
}

// ===========================================================================
// Discrete fallback pipeline (round-7, known-good)
// ===========================================================================
__global__ __launch_bounds__(256) void prep_w_kernel(
    const float* __restrict__ Wq, const float* __restrict__ Wk,
    const float* __restrict__ Wv, __hip_bfloat16* __restrict__ Wt,
    int* __restrict__ counts)
{
    const int i = blockIdx.x * 256 + threadIdx.x;
    if (i < N_NODES) counts[i] = 0;
    if (i >= 3 * D * D) return;
    const int p = i >> 14;
    const int r = i & (D * D - 1);
    const int col = r >> 7;
    const int k = r & (D - 1);
    const float* W = (p == 0) ? Wq : (p == 1) ? Wk : Wv;
    Wt[i] = __float2bfloat16(W[k * D + col]);
}

__global__ __launch_bounds__(256) void proj_hist_kernel(
    const float* __restrict__ x,
    const __hip_bfloat16* __restrict__ Wt,
    const float* __restrict__ bq, const float* __restrict__ bk,
    const float* __restrict__ bv,
    unsigned short* __restrict__ Qb, unsigned int* __restrict__ KVi,
    const int* __restrict__ dst, int* __restrict__ counts)
{
    const int tid = threadIdx.x;
    __shared__ short xs[64][136];
    if (blockIdx.x < PROJ_SPLIT) {
        const short* Wts = (const short*)Wt;
        proj_tile(blockIdx.x * 2 * 64,       tid, x, Wts, bq, bk, bv, Qb, KVi, xs);
        proj_tile((blockIdx.x * 2 + 1) * 64, tid, x, Wts, bq, bk, bv, Qb, KVi, xs);
    } else {
        hist_loop(blockIdx.x - PROJ_SPLIT, HIST_BLOCKS, tid, dst, counts);
    }
}

__global__ __launch_bounds__(SCAN_T) void scan_kernel(
    const int* __restrict__ counts, int* __restrict__ row_ptr,
    int* __restrict__ cursor)
{
    __shared__ int wsum[16];
    const int tid  = threadIdx.x;
    const int base = tid * PER_T;

    int tot = 0;
    if (tid < 1000) {
        #pragma unroll 10
        for (int j = 0; j < PER_T; ++j) tot += counts[base + j];
    }
    int incl = tot;
    #pragma unroll
    for (int off = 1; off < 64; off <<= 1) {
        const int v = __shfl_up(incl, off);
        if ((tid & 63) >= off) incl += v;
    }
    if ((tid & 63) == 63) wsum[tid >> 6] = incl;
    __syncthreads();
    if (tid == 0) {
        int run = 0;
        #pragma unroll
        for (int w = 0; w < 16; ++w) { const int v = wsum[w]; wsum[w] = run; run += v; }
    }
    __syncthreads();
    if (tid < 1000) {
        int run = (incl - tot) + wsum[tid >> 6];
        #pragma unroll 10
        for (int j = 0; j < PER_T; ++j) {
            const int c = counts[base + j];
            row_ptr[base + j] = run;
            cursor[base + j]  = run;
            run += c;
        }
    }
    if (tid == 0) row_ptr[N_NODES] = N_EDGES;
}

__global__ __launch_bounds__(256) void scatter_kernel(
    const int* __restrict__ dst, const int* __restrict__ src,
    int* __restrict__ cursor, int* __restrict__ srcs)
{
    const int i = blockIdx.x * blockDim.x + threadIdx.x;
    const int stride = gridDim.x * blockDim.x;
    for (int e = i; e < N_EDGES; e += stride) {
        const int pos = atomicAdd(&cursor[dst[e]], 1);
        srcs[pos] = src[e];
    }
}

// ===========================================================================
// Aggregate: one wave per dst node, 4 edges/iter (unchanged, 64 us)
// ===========================================================================
__global__ __launch_bounds__(256) void aggregate_kernel(
    const int* __restrict__ row_ptr, const int* __restrict__ srcs,
    const unsigned short* __restrict__ Qb, const unsigned int* __restrict__ KVi,
    const float* __restrict__ x, float* __restrict__ out)
{
    const int lane = threadIdx.x & 63;
    const int t    = (blockIdx.x * blockDim.x + threadIdx.x) >> 6;
    if (t >= N_NODES) return;

    const unsigned int qbits = *(const unsigned int*)(Qb + (size_t)t * D + 2 * lane);
    const float q0 = bfbits2f((unsigned short)(qbits & 0xffff));
    const float q1 = bfbits2f((unsigned short)(qbits >> 16));

    int i = row_ptr[t];
    const int rp1 = row_ptr[t + 1];

    float accx = 0.f, accy = 0.f, zh = 0.f;
    const unsigned long long* KVs = (const unsigned long long*)KVi;

    for (; i + 4 <= rp1; i += 4) {
        const int s0 = srcs[i + 0];
        const int s1 = srcs[i + 1];
        const int s2 = srcs[i + 2];
        const int s3 = srcs[i + 3];
        const unsigned long long kv0 = KVs[(size_t)s0 * 64 + lane];
        const unsigned long long kv1 = KVs[(size_t)s1 * 64 + lane];
        const unsigned long long kv2 = KVs[(size_t)s2 * 64 + lane];
        const unsigned long long kv3 = KVs[(size_t)s3 * 64 + lane];

        float p0 = bfbits2f((unsigned short)kv0) * q0 + bfbits2f((unsigned short)(kv0 >> 32)) * q1;
        float p1 = bfbits2f((unsigned short)kv1) * q0 + bfbits2f((unsigned short)(kv1 >> 32)) * q1;
        float p2 = bfbits2f((unsigned short)kv2) * q0 + bfbits2f((unsigned short)(kv2 >> 32)) * q1;
        float p3 = bfbits2f((unsigned short)kv3) * q0 + bfbits2f((unsigned short)(kv3 >> 32)) * q1;

        p0 += __shfl_xor(p0, 1); p1 += __shfl_xor(p1, 1);
        p2 += __shfl_xor(p2, 1); p3 += __shfl_xor(p3, 1);
        p0 += __shfl_xor(p0, 2); p1 += __shfl_xor(p1, 2);
        p2 += __shfl_xor(p2, 2); p3 += __shfl_xor(p3, 2);
        p0 += __shfl_xor(p0, 4); p1 += __shfl_xor(p1, 4);
        p2 += __shfl_xor(p2, 4); p3 += __shfl_xor(p3, 4);

        const float w0 = __expf(fminf(fmaxf(p0 * 0.25f, -5.0f), 5.0f));
        const float w1 = __expf(fminf(fmaxf(p1 * 0.25f, -5.0f), 5.0f));
        const float w2 = __expf(fminf(fmaxf(p2 * 0.25f, -5.0f), 5.0f));
        const float w3 = __expf(fminf(fmaxf(p3 * 0.25f, -5.0f), 5.0f));

        accx += w0 * bfbits2f((unsigned short)(kv0 >> 16)) + w1 * bfbits2f((unsigned short)(kv1 >> 16))
              + w2 * bfbits2f((unsigned short)(kv2 >> 16)) + w3 * bfbits2f((unsigned short)(kv3 >> 16));
        accy += w0 * bfbits2f((unsigned short)(kv0 >> 48)) + w1 * bfbits2f((unsigned short)(kv1 >> 48))
              + w2 * bfbits2f((unsigned short)(kv2 >> 48)) + w3 * bfbits2f((unsigned short)(kv3 >> 48));
        zh   += (w0 + w1) + (w2 + w3);
    }
    for (; i < rp1; ++i) {
        const int s = srcs[i];
        const unsigned long long kv = KVs[(size_t)s * 64 + lane];
        float p = bfbits2f((unsigned short)kv) * q0 + bfbits2f((unsigned short)(kv >> 32)) * q1;
        p += __shfl_xor(p, 1);
        p += __shfl_xor(p, 2);
        p += __shfl_xor(p, 4);
        const float w = __expf(fminf(fmaxf(p * 0.25f, -5.0f), 5.0f));
        accx += w * bfbits2f((unsigned short)(kv >> 16));
        accy += w * bfbits2f((unsigned short)(kv >> 48));
        zh   += w;
    }

    const float inv = 1.0f / zh;
    const int base = t * D + 2 * lane;
    out[base + 0] = x[base + 0] + accx * inv;
    out[base + 1] = x[base + 1] + accy * inv;
}

// ---------------------------------------------------------------------------
extern "C" void kernel_launch(void* const* d_in, const int* in_sizes, int n_in,
                              void* d_out, int out_size, void* d_ws, size_t ws_size,
                              hipStream_t stream) {
    const float* x   = (const float*)d_in[0];
    const int*   src = (const int*)d_in[1];
    const int*   dst = (const int*)d_in[2];
    const float* Wq  = (const float*)d_in[3];
    const float* bq  = (const float*)d_in[4];
    const float* Wk  = (const float*)d_in[5];
    const float* bk  = (const float*)d_in[6];
    const float* Wv  = (const float*)d_in[7];
    const float* bv  = (const float*)d_in[8];

    unsigned short* Qb  = (unsigned short*)d_ws;                        // [N][128] bf16
    unsigned int*   KVi = (unsigned int*)(Qb + (size_t)N_NODES * D);    // [N][128] u32
    __hip_bfloat16* Wt  = (__hip_bfloat16*)(KVi + (size_t)N_NODES * 128);
    int* counts   = (int*)(Wt + 3 * D * D);                             // [N]
    int* row_ptr  = counts + 50048;                                     // [N+1]
    int* cursor   = row_ptr + 50048;                                    // [N]
    int* blksum   = cursor + 50048;                                     // [512]
    int* srcs     = blksum + 512;                                       // [E]

    float* out = (float*)d_out;

    // --- try the cooperative single-kernel build; fall back to discrete ---
    int occ = 0;
    hipError_t oe = hipOccupancyMaxActiveBlocksPerMultiprocessor(
        &occ, build_kernel, 256, 0);
    bool coop_ok = (oe == hipSuccess) && (occ >= 2);

    if (coop_ok) {
        void* args[] = {
            (void*)&x, (void*)&src, (void*)&dst,
            (void*)&Wq, (void*)&bq, (void*)&Wk, (void*)&bk, (void*)&Wv, (void*)&bv,
            (void*)&Wt, (void*)&Qb, (void*)&KVi,
            (void*)&counts, (void*)&row_ptr, (void*)&cursor, (void*)&blksum,
            (void*)&srcs
        };
        hipError_t le = hipLaunchCooperativeKernel(
            (void*)build_kernel, dim3(COOP_BLOCKS), dim3(256), args, 0, stream);
        if (le != hipSuccess) coop_ok = false;
    }

    if (!coop_ok) {
        prep_w_kernel<<<196, 256, 0, stream>>>(Wq, Wk, Wv, Wt, counts);
        proj_hist_kernel<<<PROJ_SPLIT + HIST_BLOCKS, 256, 0, stream>>>(
            x, Wt, bq, bk, bv, Qb, KVi, dst, counts);
        scan_kernel<<<1, SCAN_T, 0, stream>>>(counts, row_ptr, cursor);
        scatter_kernel<<<1024, 256, 0, stream>>>(dst, src, cursor, srcs);
    }

    aggregate_kernel<<<(N_NODES * 64 + 255) / 256, 256, 0, stream>>>(
        row_ptr, srcs, Qb, KVi, x, out);
}